// Round 1
// baseline (210.760 us; speedup 1.0000x reference)
//
#include <hip/hip_runtime.h>
#include <stdint.h>

#define HH 512
#define WW 512
#define NIMG 64
#define OH 510
#define OW 510
#define NB 512
#define RPB 32            // output rows per block (last chunk: 30)
#define NCHUNK 16         // ceil(510/32)
#define WAVES 4
#define BLOCK 256

// Replicate reference binarization bit-exactly in float32:
// b = ((x*0.5 + 0.5) * 255.0) > 127.5
__device__ __forceinline__ int predbit(float x) {
    return ((x * 0.5f + 0.5f) * 255.0f > 127.5f) ? 1 : 0;
}

__global__ __launch_bounds__(BLOCK) void hist_kernel(const float* __restrict__ inp,
                                                     const float* __restrict__ tgt,
                                                     int* __restrict__ ghist) {
    // bit-packed binarized rows: 512 bits = 8 u64 per row, +1 pad word for funnel reads
    __shared__ unsigned long long bits[RPB + 2][9];
    __shared__ int hist[NB];

    const int tid  = threadIdx.x;
    const int lane = tid & 63;
    const int wave = tid >> 6;
    const int chunk = blockIdx.x;
    const int img   = blockIdx.y;
    const int r0 = chunk * RPB;                 // first output row of this chunk
    const int R  = min(RPB, OH - r0);           // output rows this chunk (32 or 30)
    const int rows_in = R + 2;                  // input rows needed

    for (int i = tid; i < NB; i += BLOCK) hist[i] = 0;

    const float* srcs[2] = {inp, tgt};
    for (int t = 0; t < 2; ++t) {
        const float* src = srcs[t] + (size_t)img * HH * WW + (size_t)r0 * WW;
        __syncthreads();   // hist init done (t=0) / previous code phase done (t=1)

        // ---- stage: binarize + bit-pack rows into LDS via ballot ----
        const int units = rows_in * 8;          // 8 x 64-pixel segments per row
        #pragma unroll 4
        for (int u = wave; u < units; u += WAVES) {
            int row = u >> 3, seg = u & 7;
            float x = src[row * WW + seg * 64 + lane];
            unsigned long long m = __ballot(predbit(x));  // bit L = pixel seg*64+L
            if (lane == 0) bits[row][seg] = m;
        }
        __syncthreads();

        // ---- codes: lane L handles output cols 8L..8L+7 (lane 63: 6 cols) ----
        const int sign = 1 - 2 * t;
        const int cmax = min(8, OW - 8 * lane);
        const int word = lane >> 3;
        const int sh   = (8 * lane) & 63;
        for (int o = wave; o < R; o += WAVES) {
            unsigned long long a0 = bits[o][word],     b0 = bits[o][word + 1];
            unsigned long long a1 = bits[o + 1][word], b1 = bits[o + 1][word + 1];
            unsigned long long a2 = bits[o + 2][word], b2 = bits[o + 2][word + 1];
            // safe funnel even when sh==0: (b<<1)<<(63-sh)
            unsigned long long v0 = (a0 >> sh) | ((b0 << 1) << (63 - sh));
            unsigned long long v1 = (a1 >> sh) | ((b1 << 1) << (63 - sh));
            unsigned long long v2 = (a2 >> sh) | ((b2 << 1) << (63 - sh));
            #pragma unroll
            for (int c = 0; c < 8; ++c) {
                if (c < cmax) {
                    // any consistent bijective 9-bit encoding works (bin-permutation
                    // invariance of histogram MSE)
                    int code = (int)(v0 & 7) | ((int)(v1 & 7) << 3) | ((int)(v2 & 7) << 6);
                    atomicAdd(&hist[code], sign);
                }
                v0 >>= 1; v1 >>= 1; v2 >>= 1;
            }
        }
    }

    __syncthreads();
    for (int i = tid; i < NB; i += BLOCK) {
        int v = hist[i];
        if (v) atomicAdd(&ghist[i], v);
    }
}

__global__ __launch_bounds__(NB) void reduce_kernel(const int* __restrict__ ghist,
                                                    float* __restrict__ out) {
    __shared__ double sdata[NB];
    int tid = threadIdx.x;
    double d = (double)ghist[tid];
    sdata[tid] = d * d;
    __syncthreads();
    for (int s = NB / 2; s > 0; s >>= 1) {
        if (tid < s) sdata[tid] += sdata[tid + s];
        __syncthreads();
    }
    if (tid == 0) {
        const double n = (double)NIMG * OH * OW;   // 16,646,400
        out[0] = (float)(sdata[0] / (n * n) / 512.0 / 64.0);
    }
}

extern "C" void kernel_launch(void* const* d_in, const int* in_sizes, int n_in,
                              void* d_out, int out_size, void* d_ws, size_t ws_size,
                              hipStream_t stream) {
    const float* inp = (const float*)d_in[0];
    const float* tgt = (const float*)d_in[1];
    float* out = (float*)d_out;
    int* ghist = (int*)d_ws;                    // 512 ints in workspace

    hipMemsetAsync(ghist, 0, NB * sizeof(int), stream);
    hist_kernel<<<dim3(NCHUNK, NIMG), BLOCK, 0, stream>>>(inp, tgt, ghist);
    reduce_kernel<<<1, NB, 0, stream>>>(ghist, out);
}

// Round 2
// 169.414 us; speedup vs baseline: 1.2441x; 1.2441x over previous
//
#include <hip/hip_runtime.h>
#include <stdint.h>

#define HH 512
#define WW 512
#define NIMG 64
#define OH 510
#define OW 510
#define NB 512
#define RPB 16            // output rows per block (last chunk: 14)
#define NCHUNK 32         // ceil(510/16)
#define NREP 64           // replicated global histograms (contention /64)
#define WAVES 4
#define BLOCK 256

// Replicate reference binarization bit-exactly in float32:
// b = ((x*0.5 + 0.5) * 255.0) > 127.5
__device__ __forceinline__ int predbit(float x) {
    return ((x * 0.5f + 0.5f) * 255.0f > 127.5f) ? 1 : 0;
}

__global__ __launch_bounds__(BLOCK) void hist_kernel(const float* __restrict__ inp,
                                                     const float* __restrict__ tgt,
                                                     int* __restrict__ rep) {
    // bit-packed binarized rows: 512 bits = 8 u64 per row, +1 pad word for funnel reads
    __shared__ unsigned long long bits[RPB + 2][9];
    __shared__ int hist[NB];

    const int tid  = threadIdx.x;
    const int lane = tid & 63;
    const int wave = tid >> 6;
    const int chunk = blockIdx.x;
    const int img   = blockIdx.y;
    const int r0 = chunk * RPB;                 // first output row of this chunk
    const int R  = min(RPB, OH - r0);           // output rows this chunk (16 or 14)
    const int rows_in = R + 2;                  // input rows needed

    for (int i = tid; i < NB; i += BLOCK) hist[i] = 0;

    const float* srcs[2] = {inp, tgt};
    for (int t = 0; t < 2; ++t) {
        const float* src = srcs[t] + (size_t)img * HH * WW + (size_t)r0 * WW;
        __syncthreads();   // hist init done (t=0) / previous code phase done (t=1)

        // ---- stage: binarize + bit-pack rows into LDS via ballot ----
        const int units = rows_in * 8;          // 8 x 64-pixel segments per row
        #pragma unroll 4
        for (int u = wave; u < units; u += WAVES) {
            int row = u >> 3, seg = u & 7;
            float x = src[row * WW + seg * 64 + lane];
            unsigned long long m = __ballot(predbit(x));  // bit L = pixel seg*64+L
            if (lane == 0) bits[row][seg] = m;
        }
        __syncthreads();

        // ---- codes: lane L handles output cols 8L..8L+7 (lane 63: 6 cols) ----
        const int sign = 1 - 2 * t;
        const int cmax = min(8, OW - 8 * lane);
        const int word = lane >> 3;
        const int sh   = (8 * lane) & 63;
        for (int o = wave; o < R; o += WAVES) {
            unsigned long long a0 = bits[o][word],     b0 = bits[o][word + 1];
            unsigned long long a1 = bits[o + 1][word], b1 = bits[o + 1][word + 1];
            unsigned long long a2 = bits[o + 2][word], b2 = bits[o + 2][word + 1];
            // safe funnel even when sh==0: (b<<1)<<(63-sh)
            unsigned long long v0 = (a0 >> sh) | ((b0 << 1) << (63 - sh));
            unsigned long long v1 = (a1 >> sh) | ((b1 << 1) << (63 - sh));
            unsigned long long v2 = (a2 >> sh) | ((b2 << 1) << (63 - sh));
            #pragma unroll
            for (int c = 0; c < 8; ++c) {
                if (c < cmax) {
                    // any consistent bijective 9-bit encoding works (bin-permutation
                    // invariance of histogram MSE)
                    int code = (int)(v0 & 7) | ((int)(v1 & 7) << 3) | ((int)(v2 & 7) << 6);
                    atomicAdd(&hist[code], sign);
                }
                v0 >>= 1; v1 >>= 1; v2 >>= 1;
            }
        }
    }

    __syncthreads();
    // flush to one of NREP replicated global histograms (contention /NREP)
    const int rid = (blockIdx.y * NCHUNK + blockIdx.x) & (NREP - 1);
    for (int i = tid; i < NB; i += BLOCK) {
        int v = hist[i];
        if (v) atomicAdd(&rep[rid * NB + i], v);
    }
}

__global__ __launch_bounds__(NB) void reduce_kernel(const int* __restrict__ rep,
                                                    float* __restrict__ out) {
    __shared__ double sdata[NB];
    int tid = threadIdx.x;
    int s = 0;
    #pragma unroll
    for (int r = 0; r < NREP; ++r) s += rep[r * NB + tid];   // coalesced across tid
    double d = (double)s;
    sdata[tid] = d * d;
    __syncthreads();
    for (int stp = NB / 2; stp > 0; stp >>= 1) {
        if (tid < stp) sdata[tid] += sdata[tid + stp];
        __syncthreads();
    }
    if (tid == 0) {
        const double n = (double)NIMG * OH * OW;   // 16,646,400
        out[0] = (float)(sdata[0] / (n * n) / 512.0 / 64.0);
    }
}

extern "C" void kernel_launch(void* const* d_in, const int* in_sizes, int n_in,
                              void* d_out, int out_size, void* d_ws, size_t ws_size,
                              hipStream_t stream) {
    const float* inp = (const float*)d_in[0];
    const float* tgt = (const float*)d_in[1];
    float* out = (float*)d_out;
    int* rep = (int*)d_ws;                      // NREP*NB ints = 128 KB in workspace

    hipMemsetAsync(rep, 0, NREP * NB * sizeof(int), stream);
    hist_kernel<<<dim3(NCHUNK, NIMG), BLOCK, 0, stream>>>(inp, tgt, rep);
    reduce_kernel<<<1, NB, 0, stream>>>(rep, out);
}

// Round 3
// 156.572 us; speedup vs baseline: 1.3461x; 1.0820x over previous
//
#include <hip/hip_runtime.h>
#include <stdint.h>

#define HH 512
#define WW 512
#define NIMG 64
#define OH 510
#define OW 510
#define NB 512
#define RPB 16            // output rows per block (last chunk: 14)
#define NCHUNK 32         // ceil(510/16)
#define NREP 64           // replicated global histograms (contention /64)
#define WAVES 4
#define BLOCK 256

// Replicate reference binarization bit-exactly in float32:
// b = ((x*0.5 + 0.5) * 255.0) > 127.5
__device__ __forceinline__ int predbit(float x) {
    return ((x * 0.5f + 0.5f) * 255.0f > 127.5f) ? 1 : 0;
}

__global__ __launch_bounds__(BLOCK) void hist_kernel(const float* __restrict__ inp,
                                                     const float* __restrict__ tgt,
                                                     int* __restrict__ rep) {
    // bit-packed binarized rows for BOTH tensors: 512 bits = 8 u64/row + 1 pad word
    __shared__ unsigned long long bits[2][RPB + 2][9];
    __shared__ int hist[NB];

    const int tid  = threadIdx.x;
    const int lane = tid & 63;
    const int wave = tid >> 6;
    const int chunk = blockIdx.x;
    const int img   = blockIdx.y;
    const int r0 = chunk * RPB;                 // first output row of this chunk
    const int R  = min(RPB, OH - r0);           // output rows this chunk (16 or 14)
    const int rows_in = R + 2;                  // input rows needed

    for (int i = tid; i < NB; i += BLOCK) hist[i] = 0;

    const float* srcs[2] = {inp, tgt};
    const size_t base = (size_t)img * HH * WW + (size_t)r0 * WW;

    // ---- stage: one wave stages a whole row (8 x 64px segments) ----
    // 8 loads share one base address (immediate offsets), 8-deep load MLP.
    const int nstage = 2 * rows_in;             // 36 (or 32 for tail chunk)
    for (int u = wave; u < nstage; u += WAVES) {
        const int t   = (u >= rows_in) ? 1 : 0;
        const int row = (u >= rows_in) ? u - rows_in : u;
        const float* src = srcs[t] + base + (size_t)row * WW + lane;
        float x[8];
        #pragma unroll
        for (int s = 0; s < 8; ++s) x[s] = src[s * 64];
        unsigned long long m[8];
        #pragma unroll
        for (int s = 0; s < 8; ++s) m[s] = __ballot(predbit(x[s]));
        if (lane == 0) {
            #pragma unroll
            for (int s = 0; s < 8; ++s) bits[t][row][s] = m[s];
        }
    }
    __syncthreads();

    // ---- codes: wave owns 4 consecutive output rows; lane L -> cols 8L..8L+7 ----
    const int word = lane >> 3;
    const int sh   = (8 * lane) & 63;
    const int cmax = min(8, OW - 8 * lane);     // lane 63: 6 cols
    const int rbase = wave * 4;
    for (int t = 0; t < 2; ++t) {
        const int sign = 1 - 2 * t;
        // all 6 needed row-windows loaded up front: 12 ds_reads in flight at once
        unsigned long long w[6];
        #pragma unroll
        for (int j = 0; j < 6; ++j) {
            unsigned long long a = bits[t][rbase + j][word];
            unsigned long long b = bits[t][rbase + j][word + 1];
            // safe funnel even when sh==0: (b<<1)<<(63-sh)
            w[j] = (a >> sh) | ((b << 1) << (63 - sh));
        }
        #pragma unroll
        for (int r = 0; r < 4; ++r) {
            if (rbase + r < R) {
                unsigned long long v0 = w[r], v1 = w[r + 1], v2 = w[r + 2];
                #pragma unroll
                for (int c = 0; c < 8; ++c) {
                    if (c < cmax) {
                        // any consistent bijective 9-bit encoding works
                        // (bin-permutation invariance of histogram MSE)
                        int code = (int)((v0 >> c) & 7)
                                 | ((int)((v1 >> c) & 7) << 3)
                                 | ((int)((v2 >> c) & 7) << 6);
                        atomicAdd(&hist[code], sign);
                    }
                }
            }
        }
    }

    __syncthreads();
    // flush to one of NREP replicated global histograms (contention /NREP)
    const int rid = (blockIdx.y * NCHUNK + blockIdx.x) & (NREP - 1);
    for (int i = tid; i < NB; i += BLOCK) {
        int v = hist[i];
        if (v) atomicAdd(&rep[rid * NB + i], v);
    }
}

__global__ __launch_bounds__(NB) void reduce_kernel(const int* __restrict__ rep,
                                                    float* __restrict__ out) {
    __shared__ double sdata[NB];
    int tid = threadIdx.x;
    int s = 0;
    #pragma unroll
    for (int r = 0; r < NREP; ++r) s += rep[r * NB + tid];   // coalesced across tid
    double d = (double)s;
    sdata[tid] = d * d;
    __syncthreads();
    for (int stp = NB / 2; stp > 0; stp >>= 1) {
        if (tid < stp) sdata[tid] += sdata[tid + stp];
        __syncthreads();
    }
    if (tid == 0) {
        const double n = (double)NIMG * OH * OW;   // 16,646,400
        out[0] = (float)(sdata[0] / (n * n) / 512.0 / 64.0);
    }
}

extern "C" void kernel_launch(void* const* d_in, const int* in_sizes, int n_in,
                              void* d_out, int out_size, void* d_ws, size_t ws_size,
                              hipStream_t stream) {
    const float* inp = (const float*)d_in[0];
    const float* tgt = (const float*)d_in[1];
    float* out = (float*)d_out;
    int* rep = (int*)d_ws;                      // NREP*NB ints = 128 KB in workspace

    hipMemsetAsync(rep, 0, NREP * NB * sizeof(int), stream);
    hist_kernel<<<dim3(NCHUNK, NIMG), BLOCK, 0, stream>>>(inp, tgt, rep);
    reduce_kernel<<<1, NB, 0, stream>>>(rep, out);
}

// Round 4
// 152.531 us; speedup vs baseline: 1.3818x; 1.0265x over previous
//
#include <hip/hip_runtime.h>
#include <stdint.h>

#define HH 512
#define WW 512
#define NIMG 64
#define OH 510
#define OW 510
#define NB 512
#define RPB 16            // output rows per block (last chunk: 14)
#define NCHUNK 32         // ceil(510/16)
#define NREP 64           // replicated global histograms (contention /64)
#define WAVES 4
#define BLOCK 256
#define UMAX 9            // ceil(2*(RPB+2)/WAVES) stage units per wave

// Replicate reference binarization bit-exactly in float32:
// b = ((x*0.5 + 0.5) * 255.0) > 127.5
__device__ __forceinline__ int predbit(float x) {
    return ((x * 0.5f + 0.5f) * 255.0f > 127.5f) ? 1 : 0;
}

__global__ __launch_bounds__(BLOCK) void hist_kernel(const float* __restrict__ inp,
                                                     const float* __restrict__ tgt,
                                                     int* __restrict__ rep) {
    // bit-packed binarized rows for BOTH tensors: 512 bits = 8 u64/row + 1 pad word
    __shared__ unsigned long long bits[2][RPB + 2][9];
    __shared__ int hist[NB];

    const int tid  = threadIdx.x;
    const int lane = tid & 63;
    const int wave = tid >> 6;
    const int chunk = blockIdx.x;
    const int img   = blockIdx.y;
    const int r0 = chunk * RPB;                 // first output row of this chunk
    const int R  = min(RPB, OH - r0);           // output rows this chunk (16 or 14)
    const int rows_in = R + 2;                  // input rows needed
    const int nstage = 2 * rows_in;             // 36 (32 for tail chunk) -> k=8 unit
                                                // is the only conditional one

    for (int i = tid; i < NB; i += BLOCK) hist[i] = 0;

    const float* srcs[2] = {inp, tgt};
    const size_t base = (size_t)img * HH * WW + (size_t)r0 * WW;

    // ---- stage pass 1: issue ALL loads first (up to 72 in flight per wave) ----
    float xv[UMAX][8];
    #pragma unroll
    for (int k = 0; k < UMAX; ++k) {
        const int u = wave + k * WAVES;
        if (k < UMAX - 1 || u < nstage) {       // only k=8 needs the runtime guard
            const int t   = (u >= rows_in) ? 1 : 0;
            const int row = (u >= rows_in) ? u - rows_in : u;
            const float* src = srcs[t] + base + (size_t)row * WW + lane;
            #pragma unroll
            for (int s = 0; s < 8; ++s) xv[k][s] = src[s * 64];
        }
    }

    // ---- stage pass 2: ballot + bit-pack into LDS ----
    #pragma unroll
    for (int k = 0; k < UMAX; ++k) {
        const int u = wave + k * WAVES;
        if (k < UMAX - 1 || u < nstage) {
            const int t   = (u >= rows_in) ? 1 : 0;
            const int row = (u >= rows_in) ? u - rows_in : u;
            unsigned long long m[8];
            #pragma unroll
            for (int s = 0; s < 8; ++s) m[s] = __ballot(predbit(xv[k][s]));
            if (lane == 0) {
                #pragma unroll
                for (int s = 0; s < 8; ++s) bits[t][row][s] = m[s];
            }
        }
    }
    __syncthreads();

    // ---- codes: wave owns 4 consecutive output rows; lane L -> cols 8L..8L+7 ----
    const int word = lane >> 3;
    const int sh   = (8 * lane) & 63;
    const int cmax = min(8, OW - 8 * lane);     // lane 63: 6 cols
    const int rbase = wave * 4;
    for (int t = 0; t < 2; ++t) {
        const int sign = 1 - 2 * t;
        // all 6 needed row-windows loaded up front: 12 ds_reads in flight at once
        unsigned long long w[6];
        #pragma unroll
        for (int j = 0; j < 6; ++j) {
            unsigned long long a = bits[t][rbase + j][word];
            unsigned long long b = bits[t][rbase + j][word + 1];
            // safe funnel even when sh==0: (b<<1)<<(63-sh)
            w[j] = (a >> sh) | ((b << 1) << (63 - sh));
        }
        #pragma unroll
        for (int r = 0; r < 4; ++r) {
            if (rbase + r < R) {
                unsigned long long v0 = w[r], v1 = w[r + 1], v2 = w[r + 2];
                #pragma unroll
                for (int c = 0; c < 8; ++c) {
                    if (c < cmax) {
                        // any consistent bijective 9-bit encoding works
                        // (bin-permutation invariance of histogram MSE)
                        int code = (int)((v0 >> c) & 7)
                                 | ((int)((v1 >> c) & 7) << 3)
                                 | ((int)((v2 >> c) & 7) << 6);
                        atomicAdd(&hist[code], sign);
                    }
                }
            }
        }
    }

    __syncthreads();
    // flush to one of NREP replicated global histograms (contention /NREP)
    const int rid = (blockIdx.y * NCHUNK + blockIdx.x) & (NREP - 1);
    for (int i = tid; i < NB; i += BLOCK) {
        int v = hist[i];
        if (v) atomicAdd(&rep[rid * NB + i], v);
    }
}

__global__ __launch_bounds__(NB) void reduce_kernel(const int* __restrict__ rep,
                                                    float* __restrict__ out) {
    __shared__ double sdata[NB];
    int tid = threadIdx.x;
    int s = 0;
    #pragma unroll
    for (int r = 0; r < NREP; ++r) s += rep[r * NB + tid];   // coalesced across tid
    double d = (double)s;
    sdata[tid] = d * d;
    __syncthreads();
    for (int stp = NB / 2; stp > 0; stp >>= 1) {
        if (tid < stp) sdata[tid] += sdata[tid + stp];
        __syncthreads();
    }
    if (tid == 0) {
        const double n = (double)NIMG * OH * OW;   // 16,646,400
        out[0] = (float)(sdata[0] / (n * n) / 512.0 / 64.0);
    }
}

extern "C" void kernel_launch(void* const* d_in, const int* in_sizes, int n_in,
                              void* d_out, int out_size, void* d_ws, size_t ws_size,
                              hipStream_t stream) {
    const float* inp = (const float*)d_in[0];
    const float* tgt = (const float*)d_in[1];
    float* out = (float*)d_out;
    int* rep = (int*)d_ws;                      // NREP*NB ints = 128 KB in workspace

    hipMemsetAsync(rep, 0, NREP * NB * sizeof(int), stream);
    hist_kernel<<<dim3(NCHUNK, NIMG), BLOCK, 0, stream>>>(inp, tgt, rep);
    reduce_kernel<<<1, NB, 0, stream>>>(rep, out);
}